// Round 1
// baseline (111.533 us; speedup 1.0000x reference)
//
#include <hip/hip_runtime.h>
#include <math.h>

// LossLayer: dist[b,r] = ||W[b]-R[r]||2 ; pred = one_hot(argmax_r dist) ; 
// loss = mean(1 + dist[b, argmax(label[b])] - dist[b, top2-excluding-y-at-top1])
#define NB 4096
#define NR 64
#define ND 512
#define BB 16          // b-rows per block
#define NCHUNK 4       // D chunks of 128
#define RSTRIDE 33     // float4 per LDS row (132 floats): bank-step 4 -> 2-way (free)

__global__ __launch_bounds__(256) void dist_topk_kernel(
    const float* __restrict__ w,
    const float* __restrict__ re,
    const float* __restrict__ label,
    float* __restrict__ out,
    float* __restrict__ ws)
{
    __shared__ float4 wl[BB * RSTRIDE];   // 8448 B
    __shared__ float4 rl[NR * RSTRIDE];   // 33792 B

    const int tid  = threadIdx.x;
    const int bl   = tid >> 4;      // local b row 0..15
    const int rg   = tid & 15;      // r group 0..15 ; owns r = rg, rg+16, rg+32, rg+48
    const int b0   = blockIdx.x * BB;
    const int b    = b0 + bl;
    const int lane = tid & 63;

    const float4* wg  = (const float4*)w;
    const float4* rg4 = (const float4*)re;

    float4 acc0 = {0,0,0,0}, acc1 = {0,0,0,0}, acc2 = {0,0,0,0}, acc3 = {0,0,0,0};

    float4 pw[2], pr[8];
    // prefetch chunk 0
    #pragma unroll
    for (int t = 0; t < 2; t++) { int idx = tid + t*256; int row = idx >> 5; int col = idx & 31;
        pw[t] = wg[(size_t)(b0 + row)*128 + col]; }
    #pragma unroll
    for (int t = 0; t < 8; t++) { int idx = tid + t*256; int row = idx >> 5; int col = idx & 31;
        pr[t] = rg4[(size_t)row*128 + col]; }

    for (int c = 0; c < NCHUNK; c++) {
        // stage prefetched chunk into LDS
        #pragma unroll
        for (int t = 0; t < 2; t++) { int idx = tid + t*256; int row = idx >> 5; int col = idx & 31;
            wl[row*RSTRIDE + col] = pw[t]; }
        #pragma unroll
        for (int t = 0; t < 8; t++) { int idx = tid + t*256; int row = idx >> 5; int col = idx & 31;
            rl[row*RSTRIDE + col] = pr[t]; }
        __syncthreads();
        if (c + 1 < NCHUNK) {   // prefetch next chunk while computing this one
            int dc4 = (c + 1) * 32;
            #pragma unroll
            for (int t = 0; t < 2; t++) { int idx = tid + t*256; int row = idx >> 5; int col = idx & 31;
                pw[t] = wg[(size_t)(b0 + row)*128 + dc4 + col]; }
            #pragma unroll
            for (int t = 0; t < 8; t++) { int idx = tid + t*256; int row = idx >> 5; int col = idx & 31;
                pr[t] = rg4[(size_t)row*128 + dc4 + col]; }
        }
        const float4* wr = &wl[bl * RSTRIDE];            // broadcast across 16 lanes
        const float4* r0 = &rl[(rg     ) * RSTRIDE];
        const float4* r1 = &rl[(16 + rg) * RSTRIDE];
        const float4* r2 = &rl[(32 + rg) * RSTRIDE];
        const float4* r3 = &rl[(48 + rg) * RSTRIDE];
        #pragma unroll
        for (int dd = 0; dd < 32; dd++) {
            float4 w4 = wr[dd];
            float dx;
            float4 a = r0[dd];
            dx = w4.x - a.x; acc0.x = fmaf(dx, dx, acc0.x);
            dx = w4.y - a.y; acc0.y = fmaf(dx, dx, acc0.y);
            dx = w4.z - a.z; acc0.z = fmaf(dx, dx, acc0.z);
            dx = w4.w - a.w; acc0.w = fmaf(dx, dx, acc0.w);
            a = r1[dd];
            dx = w4.x - a.x; acc1.x = fmaf(dx, dx, acc1.x);
            dx = w4.y - a.y; acc1.y = fmaf(dx, dx, acc1.y);
            dx = w4.z - a.z; acc1.z = fmaf(dx, dx, acc1.z);
            dx = w4.w - a.w; acc1.w = fmaf(dx, dx, acc1.w);
            a = r2[dd];
            dx = w4.x - a.x; acc2.x = fmaf(dx, dx, acc2.x);
            dx = w4.y - a.y; acc2.y = fmaf(dx, dx, acc2.y);
            dx = w4.z - a.z; acc2.z = fmaf(dx, dx, acc2.z);
            dx = w4.w - a.w; acc2.w = fmaf(dx, dx, acc2.w);
            a = r3[dd];
            dx = w4.x - a.x; acc3.x = fmaf(dx, dx, acc3.x);
            dx = w4.y - a.y; acc3.y = fmaf(dx, dx, acc3.y);
            dx = w4.z - a.z; acc3.z = fmaf(dx, dx, acc3.z);
            dx = w4.w - a.w; acc3.w = fmaf(dx, dx, acc3.w);
        }
        __syncthreads();
    }

    // 4 parallel chains -> low accumulation error (~5e-5 in dist^2)
    float d0 = sqrtf((acc0.x + acc0.y) + (acc0.z + acc0.w));
    float d1 = sqrtf((acc1.x + acc1.y) + (acc1.z + acc1.w));
    float d2 = sqrtf((acc2.x + acc2.y) + (acc2.z + acc2.w));
    float d3 = sqrtf((acc3.x + acc3.y) + (acc3.z + acc3.w));

    // local top-2 over (d0..d3), r ascending (rg, 16+rg, 32+rg, 48+rg) with strict >
    float m1 = d0; int i1 = rg; float m2 = -3.0e38f; int i2 = -1;
    if (d1 > m1) { m2 = m1; i2 = i1; m1 = d1; i1 = 16 + rg; } else if (d1 > m2) { m2 = d1; i2 = 16 + rg; }
    if (d2 > m1) { m2 = m1; i2 = i1; m1 = d2; i1 = 32 + rg; } else if (d2 > m2) { m2 = d2; i2 = 32 + rg; }
    if (d3 > m1) { m2 = m1; i2 = i1; m1 = d3; i1 = 48 + rg; } else if (d3 > m2) { m2 = d3; i2 = 48 + rg; }

    // butterfly merge across the 16 lanes sharing b (first-index tie-break)
    #pragma unroll
    for (int mask = 1; mask <= 8; mask <<= 1) {
        float om1 = __shfl_xor(m1, mask, 64); int oi1 = __shfl_xor(i1, mask, 64);
        float om2 = __shfl_xor(m2, mask, 64); int oi2 = __shfl_xor(i2, mask, 64);
        bool ob1 = (om1 > m1) || (om1 == m1 && oi1 < i1);
        float w1 = ob1 ? om1 : m1;  int wi1 = ob1 ? oi1 : i1;
        float l1 = ob1 ? m1 : om1;  int li1 = ob1 ? i1 : oi1;
        float c2 = ob1 ? om2 : m2;  int ci2 = ob1 ? oi2 : i2;
        bool sb = (c2 > l1) || (c2 == l1 && ci2 < li1);
        m1 = w1; i1 = wi1;
        m2 = sb ? c2 : l1; i2 = sb ? ci2 : li1;
    }

    // y = argmax(label[b]) ; lane rg reads elements rg*4..rg*4+3 (coalesced float4)
    float4 lb = ((const float4*)label)[(size_t)b * 16 + rg];
    float lv = lb.x; int ly = rg * 4;
    if (lb.y > lv) { lv = lb.y; ly = rg * 4 + 1; }
    if (lb.z > lv) { lv = lb.z; ly = rg * 4 + 2; }
    if (lb.w > lv) { lv = lb.w; ly = rg * 4 + 3; }
    #pragma unroll
    for (int mask = 1; mask <= 8; mask <<= 1) {
        float ov = __shfl_xor(lv, mask, 64); int oy = __shfl_xor(ly, mask, 64);
        if (ov > lv || (ov == lv && oy < ly)) { lv = ov; ly = oy; }
    }
    int y = ly;

    // plus = dist[b][y]: owner lane has rg == (y & 15), slot j = y >> 4
    int jy = y >> 4;
    float myv = (jy == 0) ? d0 : ((jy == 1) ? d1 : ((jy == 2) ? d2 : d3));
    int src = (lane & 48) | (y & 15);
    float plus = __shfl(myv, src, 64);

    float minus = (i1 == y) ? m2 : m1;
    if (rg == 0) ws[b] = 1.0f + plus - minus;

    // pred one-hot
    float* op = out + (size_t)b * 64;
    op[rg]      = (i1 == rg)      ? 1.0f : 0.0f;
    op[16 + rg] = (i1 == 16 + rg) ? 1.0f : 0.0f;
    op[32 + rg] = (i1 == 32 + rg) ? 1.0f : 0.0f;
    op[48 + rg] = (i1 == 48 + rg) ? 1.0f : 0.0f;
}

__global__ __launch_bounds__(256) void loss_reduce_kernel(
    const float* __restrict__ ws, float* __restrict__ out)
{
    int tid = threadIdx.x;
    float s = 0.0f;
    #pragma unroll
    for (int k = 0; k < 16; k++) s += ws[tid + 256 * k];
    #pragma unroll
    for (int m = 1; m < 64; m <<= 1) s += __shfl_xor(s, m, 64);
    __shared__ float part[4];
    if ((tid & 63) == 0) part[tid >> 6] = s;
    __syncthreads();
    if (tid == 0) out[(size_t)NB * NR] = (part[0] + part[1] + part[2] + part[3]) * (1.0f / NB);
}

extern "C" void kernel_launch(void* const* d_in, const int* in_sizes, int n_in,
                              void* d_out, int out_size, void* d_ws, size_t ws_size,
                              hipStream_t stream) {
    const float* w   = (const float*)d_in[0];   // [4096,512]
    const float* re  = (const float*)d_in[1];   // [64,512]
    const float* lab = (const float*)d_in[2];   // [4096,64]
    float* out = (float*)d_out;                 // pred [4096,64] ++ loss [1]
    float* ws  = (float*)d_ws;                  // per-b loss terms [4096]

    dist_topk_kernel<<<NB / BB, 256, 0, stream>>>(w, re, lab, out, ws);
    loss_reduce_kernel<<<1, 256, 0, stream>>>(ws, out);
}